// Round 1
// baseline (453.381 us; speedup 1.0000x reference)
//
#include <hip/hip_runtime.h>
#include <stdint.h>

#define DIM 2048

typedef short short8 __attribute__((ext_vector_type(8)));
typedef float f32x4 __attribute__((ext_vector_type(4)));

__device__ __forceinline__ unsigned short f2bf(float f) {
    union { float f; unsigned int u; } v;
    v.f = f;
    unsigned int r = v.u + 0x7FFFu + ((v.u >> 16) & 1u);  // round-to-nearest-even
    return (unsigned short)(r >> 16);
}
__device__ __forceinline__ float bf2f(unsigned short u) {
    union { unsigned int u; float f; } v;
    v.u = ((unsigned int)u) << 16;
    return v.f;
}

// async global->LDS, 16B per lane. LDS dest must be wave-uniform base + lane*16.
__device__ __forceinline__ void async16(const unsigned short* g, unsigned short* l) {
    __builtin_amdgcn_global_load_lds(
        (__attribute__((address_space(1))) void*)(uintptr_t)g,
        (__attribute__((address_space(3))) void*)(uintptr_t)l,
        16, 0, 0);
}

// Build bf16 skew-symmetric A from angles: A[i][j]=ang[k(i,j)] (i<j), A[j][i]=-that.
__global__ void build_A(const float* __restrict__ ang, unsigned short* __restrict__ A) {
    int idx = blockIdx.x * 256 + threadIdx.x;   // one thread per element, 2048*2048
    int i = idx >> 11;
    int j = idx & 2047;
    float v = 0.0f;
    if (i < j)      v =  ang[i * (2 * DIM - 1 - i) / 2 + (j - i - 1)];
    else if (i > j) v = -ang[j * (2 * DIM - 1 - j) / 2 + (i - j - 1)];
    A[idx] = f2bf(v);
}

// fp32 -> bf16, 4 elems/thread
__global__ void cvt_f32_bf16(const float* __restrict__ in, unsigned short* __restrict__ out) {
    int i = (blockIdx.x * 256 + threadIdx.x) * 4;
    const float4 v = *(const float4*)(in + i);
    ushort4 o;
    o.x = f2bf(v.x); o.y = f2bf(v.y); o.z = f2bf(v.z); o.w = f2bf(v.w);
    *(ushort4*)(out + i) = o;
}

// NT GEMM: acc[m][n] = sum_k Aop[m][k] * Bop[n][k]   (both row-major, K contiguous)
// EPI==0:  Wt[m*N+n] = (m==n) - 2*Abf[m*N+n] - acc   (Wt = W^T = I - 2A - A*A^T, bf16)
// EPI==1:  out[m*N+n] = acc + bias[n]                 (fp32)
// 128x128 tile, BK=32, 256 threads (4 waves 2x2, each 64x64 via 4x4 mfma 16x16x32).
template <int EPI>
__global__ __launch_bounds__(256) void gemm_nt(
        const unsigned short* __restrict__ Aop,
        const unsigned short* __restrict__ Bop,
        int M, int N, int K,
        const unsigned short* __restrict__ Abf,
        unsigned short* __restrict__ Wt,
        const float* __restrict__ bias,
        float* __restrict__ out) {
    __shared__ __align__(16) unsigned short ldsA[128 * 32];
    __shared__ __align__(16) unsigned short ldsB[128 * 32];

    const int t    = threadIdx.x;
    const int bn   = blockIdx.x * 128;
    const int bm   = blockIdx.y * 128;
    const int lane = t & 63;
    const int wave = t >> 6;
    const int waveM = (wave >> 1) * 64;
    const int waveN = (wave & 1) * 64;
    const int fm = lane & 15;   // m (A) / n (B) index within 16-tile; also C col
    const int fq = lane >> 4;   // k-chunk quad; C row group

    f32x4 acc[4][4];
#pragma unroll
    for (int i = 0; i < 4; ++i)
#pragma unroll
        for (int j = 0; j < 4; ++j)
            acc[i][j] = (f32x4){0.f, 0.f, 0.f, 0.f};

    // staging: thread t loads 8 bf16 (16B) at tile row t/4, col chunk (t%4)*8,
    // twice per operand (rows t/4 and 64+t/4). LDS layout [row][k] unpadded.
    const int trow = t >> 2;
    const int tcol = (t & 3) * 8;
    const unsigned short* gA = Aop + (size_t)(bm + trow) * K + tcol;
    const unsigned short* gB = Bop + (size_t)(bn + trow) * K + tcol;
    const size_t rowskip = (size_t)64 * K;
    unsigned short* lA0 = ldsA + t * 8;
    unsigned short* lA1 = ldsA + 2048 + t * 8;
    unsigned short* lB0 = ldsB + t * 8;
    unsigned short* lB1 = ldsB + 2048 + t * 8;

    for (int kt = 0; kt < K; kt += 32) {
        __syncthreads();                    // previous tile fully consumed
        async16(gA + kt, lA0);
        async16(gA + kt + rowskip, lA1);
        async16(gB + kt, lB0);
        async16(gB + kt + rowskip, lB1);
        __syncthreads();                    // tile staged (vmcnt drained at barrier)

        short8 af[4], bfv[4];
#pragma unroll
        for (int i = 0; i < 4; ++i) {
            af[i]  = *(const short8*)(ldsA + (waveM + i * 16 + fm) * 32 + fq * 8);
            bfv[i] = *(const short8*)(ldsB + (waveN + i * 16 + fm) * 32 + fq * 8);
        }
#pragma unroll
        for (int i = 0; i < 4; ++i)
#pragma unroll
            for (int j = 0; j < 4; ++j)
                acc[i][j] = __builtin_amdgcn_mfma_f32_16x16x32_bf16(
                    af[i], bfv[j], acc[i][j], 0, 0, 0);
    }

    // epilogue: C/D layout col = lane&15, row = (lane>>4)*4 + r  [m89/m91 verified]
#pragma unroll
    for (int i = 0; i < 4; ++i) {
#pragma unroll
        for (int j = 0; j < 4; ++j) {
            const int col = bn + waveN + j * 16 + fm;
#pragma unroll
            for (int r = 0; r < 4; ++r) {
                const int row = bm + waveM + i * 16 + fq * 4 + r;
                const float s = acc[i][j][r];
                if (EPI == 0) {
                    const float a = bf2f(Abf[(size_t)row * N + col]);
                    const float w = (row == col ? 1.0f : 0.0f) - 2.0f * a - s;
                    Wt[(size_t)row * N + col] = f2bf(w);
                } else {
                    out[(size_t)row * N + col] = s + bias[col];
                }
            }
        }
    }
}

extern "C" void kernel_launch(void* const* d_in, const int* in_sizes, int n_in,
                              void* d_out, int out_size, void* d_ws, size_t ws_size,
                              hipStream_t stream) {
    const float* x      = (const float*)d_in[0];   // 4*4096*2048
    const float* angles = (const float*)d_in[1];   // 2096128
    const float* bias   = (const float*)d_in[2];   // 2048
    float* out = (float*)d_out;

    char* ws = (char*)d_ws;
    unsigned short* Abf = (unsigned short*)ws;                      //  8 MB: A bf16
    unsigned short* Wt  = (unsigned short*)(ws + (8u << 20));       //  8 MB: W^T bf16
    unsigned short* xbf = (unsigned short*)(ws + (16u << 20));      // 64 MB: x bf16

    const int M = 4 * 4096;   // 16384 rows
    const int n_elem_x = M * DIM;

    build_A<<<(DIM * DIM) / 256, 256, 0, stream>>>(angles, Abf);
    cvt_f32_bf16<<<(n_elem_x / 4) / 256, 256, 0, stream>>>(x, xbf);

    // S = A A^T, epilogue writes Wt = I - 2A - S  (2048^3)
    gemm_nt<0><<<dim3(DIM / 128, DIM / 128), 256, 0, stream>>>(
        Abf, Abf, DIM, DIM, DIM, Abf, Wt, nullptr, nullptr);

    // out = x @ W + bias  via NT against Wt  (16384 x 2048 x 2048)
    gemm_nt<1><<<dim3(DIM / 128, M / 128), 256, 0, stream>>>(
        xbf, Wt, M, DIM, DIM, nullptr, nullptr, bias, out);
}

// Round 2
// 427.736 us; speedup vs baseline: 1.0600x; 1.0600x over previous
//
#include <hip/hip_runtime.h>
#include <stdint.h>

#define DIM 2048

typedef short short8 __attribute__((ext_vector_type(8)));
typedef float f32x4 __attribute__((ext_vector_type(4)));

__device__ __forceinline__ unsigned short f2bf(float f) {
    union { float f; unsigned int u; } v;
    v.f = f;
    unsigned int r = v.u + 0x7FFFu + ((v.u >> 16) & 1u);  // round-to-nearest-even
    return (unsigned short)(r >> 16);
}
__device__ __forceinline__ float bf2f(unsigned short u) {
    union { unsigned int u; float f; } v;
    v.u = ((unsigned int)u) << 16;
    return v.f;
}

// async global->LDS, 16B per lane. LDS dest must be wave-uniform base + lane*16.
__device__ __forceinline__ void async16(const unsigned short* g, unsigned short* l) {
    __builtin_amdgcn_global_load_lds(
        (__attribute__((address_space(1))) void*)(uintptr_t)g,
        (__attribute__((address_space(3))) void*)(uintptr_t)l,
        16, 0, 0);
}

// Tiled skew-symmetric build: one block per upper-tri 64x64 tile pair.
// Reads angles coalesced (upper triangle only), stages in padded LDS,
// writes BOTH A[ti][tj] and A[tj][ti] = -A[ti][tj]^T coalesced.
__global__ __launch_bounds__(256) void build_A_tiled(const float* __restrict__ ang,
                                                     unsigned short* __restrict__ A) {
    __shared__ float tile[64][65];   // +1 pad: transposed reads conflict-free
    int b = blockIdx.x;
    int ti = 0, rem = b;
    while (rem >= 32 - ti) { rem -= 32 - ti; ++ti; }
    const int tj = ti + rem;
    const int t  = threadIdx.x;
    const int lj = t & 63;          // col within tile (coalesced dim)
    const int lw = t >> 6;          // wave id 0..3 -> row group
    const bool diag = (ti == tj);

    // phase 1: upper-tri values -> LDS (i = ti*64+li, j = tj*64+lj; fetch iff i<j)
#pragma unroll
    for (int m = 0; m < 16; ++m) {
        const int li = lw * 16 + m;
        const int i = ti * 64 + li;
        const int j = tj * 64 + lj;
        float v = 0.0f;
        if (i < j) v = ang[i * (4095 - i) / 2 + (j - i - 1)];
        tile[li][lj] = v;
    }
    __syncthreads();

    // phase 2a: write tile (ti,tj), coalesced along lj
#pragma unroll
    for (int m = 0; m < 16; ++m) {
        const int li = lw * 16 + m;
        float v;
        if (diag) {
            if (li < lj)      v =  tile[li][lj];
            else if (li > lj) v = -tile[lj][li];
            else              v = 0.0f;
        } else {
            v = tile[li][lj];
        }
        A[(size_t)(ti * 64 + li) * DIM + tj * 64 + lj] = f2bf(v);
    }
    // phase 2b: mirror tile (tj,ti) = -transpose, coalesced along lj
    if (!diag) {
#pragma unroll
        for (int m = 0; m < 16; ++m) {
            const int li = lw * 16 + m;   // row within mirror tile
            A[(size_t)(tj * 64 + li) * DIM + ti * 64 + lj] = f2bf(-tile[lj][li]);
        }
    }
}

// fp32 -> bf16, 4 elems/thread
__global__ void cvt_f32_bf16(const float* __restrict__ in, unsigned short* __restrict__ out) {
    int i = (blockIdx.x * 256 + threadIdx.x) * 4;
    const float4 v = *(const float4*)(in + i);
    ushort4 o;
    o.x = f2bf(v.x); o.y = f2bf(v.y); o.z = f2bf(v.z); o.w = f2bf(v.w);
    *(ushort4*)(out + i) = o;
}

// NT GEMM: acc[m][n] = sum_k Aop[m][k] * Bop[n][k]   (both row-major, K contiguous)
// EPI==0:  Wt[m*N+n] = (m==n) - 2*Abf[m*N+n] - acc   (Wt = W^T = I - 2A - A*A^T, bf16)
// EPI==1:  out[m*N+n] = acc + bias[n]                 (fp32)
// 128x128 tile, BK=64 (32 KB LDS), XOR bank-swizzle, 256 threads,
// 4 waves 2x2, each 64x64 via 4x4 mfma 16x16x32.
template <int EPI>
__global__ __launch_bounds__(256) void gemm_nt(
        const unsigned short* __restrict__ Aop,
        const unsigned short* __restrict__ Bop,
        int M, int N, int K,
        const unsigned short* __restrict__ Abf,
        unsigned short* __restrict__ Wt,
        const float* __restrict__ bias,
        float* __restrict__ out) {
    __shared__ __align__(16) unsigned short ldsA[128 * 64];   // 16 KB
    __shared__ __align__(16) unsigned short ldsB[128 * 64];   // 16 KB

    const int t    = threadIdx.x;
    const int bn   = blockIdx.x * 128;
    const int bm   = blockIdx.y * 128;
    const int lane = t & 63;
    const int wave = t >> 6;
    const int waveM = (wave >> 1) * 64;
    const int waveN = (wave & 1) * 64;
    const int fm = lane & 15;   // m (A) / n (B) index within 16-tile; also C col
    const int fq = lane >> 4;   // k-chunk quad; C row group

    f32x4 acc[4][4];
#pragma unroll
    for (int i = 0; i < 4; ++i)
#pragma unroll
        for (int j = 0; j < 4; ++j)
            acc[i][j] = (f32x4){0.f, 0.f, 0.f, 0.f};

    // staging: thread t covers row trow = t>>3 (+i*32), swizzled k-chunk
    // tchunk = (t&7) ^ (trow&7). LDS slot for (row, chunk c) is c ^ (row&7):
    // bank-quad per lane spans all 8 quads in a fragment read (2-way = free).
    const int trow   = t >> 3;                     // 0..31
    const int tchunk = (t & 7) ^ (trow & 7);       // source k-chunk, 0..7
    const unsigned short* gA = Aop + (size_t)(bm + trow) * K + tchunk * 8;
    const unsigned short* gB = Bop + (size_t)(bn + trow) * K + tchunk * 8;
    const size_t rowskip = (size_t)32 * K;
    unsigned short* lA = ldsA + t * 8;
    unsigned short* lB = ldsB + t * 8;

    for (int kt = 0; kt < K; kt += 64) {
        __syncthreads();                    // previous tile fully consumed
#pragma unroll
        for (int i = 0; i < 4; ++i) {
            async16(gA + kt + i * rowskip, lA + i * 2048);
            async16(gB + kt + i * rowskip, lB + i * 2048);
        }
        __syncthreads();                    // tile staged (vmcnt drained at barrier)

#pragma unroll
        for (int ks = 0; ks < 2; ++ks) {
            short8 af[4], bfv[4];
#pragma unroll
            for (int i = 0; i < 4; ++i) {
                const int rowA = waveM + i * 16 + fm;
                const int rowB = waveN + i * 16 + fm;
                af[i]  = *(const short8*)(ldsA + rowA * 64 + (((ks << 2) + fq) ^ (rowA & 7)) * 8);
                bfv[i] = *(const short8*)(ldsB + rowB * 64 + (((ks << 2) + fq) ^ (rowB & 7)) * 8);
            }
#pragma unroll
            for (int i = 0; i < 4; ++i)
#pragma unroll
                for (int j = 0; j < 4; ++j)
                    acc[i][j] = __builtin_amdgcn_mfma_f32_16x16x32_bf16(
                        af[i], bfv[j], acc[i][j], 0, 0, 0);
        }
    }

    // epilogue: C/D layout col = lane&15, row = (lane>>4)*4 + r  [m89/m91 verified]
#pragma unroll
    for (int i = 0; i < 4; ++i) {
#pragma unroll
        for (int j = 0; j < 4; ++j) {
            const int col = bn + waveN + j * 16 + fm;
#pragma unroll
            for (int r = 0; r < 4; ++r) {
                const int row = bm + waveM + i * 16 + fq * 4 + r;
                const float s = acc[i][j][r];
                if (EPI == 0) {
                    const float a = bf2f(Abf[(size_t)row * N + col]);
                    const float w = (row == col ? 1.0f : 0.0f) - 2.0f * a - s;
                    Wt[(size_t)row * N + col] = f2bf(w);
                } else {
                    out[(size_t)row * N + col] = s + bias[col];
                }
            }
        }
    }
}

extern "C" void kernel_launch(void* const* d_in, const int* in_sizes, int n_in,
                              void* d_out, int out_size, void* d_ws, size_t ws_size,
                              hipStream_t stream) {
    const float* x      = (const float*)d_in[0];   // 4*4096*2048
    const float* angles = (const float*)d_in[1];   // 2096128
    const float* bias   = (const float*)d_in[2];   // 2048
    float* out = (float*)d_out;

    char* ws = (char*)d_ws;
    unsigned short* Abf = (unsigned short*)ws;                      //  8 MB: A bf16
    unsigned short* Wt  = (unsigned short*)(ws + (8u << 20));       //  8 MB: W^T bf16
    unsigned short* xbf = (unsigned short*)(ws + (16u << 20));      // 64 MB: x bf16

    const int M = 4 * 4096;   // 16384 rows
    const int n_elem_x = M * DIM;

    build_A_tiled<<<528, 256, 0, stream>>>(angles, Abf);   // 32*33/2 tile pairs
    cvt_f32_bf16<<<(n_elem_x / 4) / 256, 256, 0, stream>>>(x, xbf);

    // S = A A^T, epilogue writes Wt = I - 2A - S  (2048^3)
    gemm_nt<0><<<dim3(DIM / 128, DIM / 128), 256, 0, stream>>>(
        Abf, Abf, DIM, DIM, DIM, Abf, Wt, nullptr, nullptr);

    // out = x @ W + bias  via NT against Wt  (16384 x 2048 x 2048)
    gemm_nt<1><<<dim3(DIM / 128, M / 128), 256, 0, stream>>>(
        xbf, Wt, M, DIM, DIM, nullptr, nullptr, bias, out);
}

// Round 3
// 410.223 us; speedup vs baseline: 1.1052x; 1.0427x over previous
//
#include <hip/hip_runtime.h>
#include <stdint.h>

#define DIM 2048

typedef short short8 __attribute__((ext_vector_type(8)));
typedef float f32x4 __attribute__((ext_vector_type(4)));

__device__ __forceinline__ unsigned short f2bf(float f) {
    union { float f; unsigned int u; } v;
    v.f = f;
    unsigned int r = v.u + 0x7FFFu + ((v.u >> 16) & 1u);  // round-to-nearest-even
    return (unsigned short)(r >> 16);
}
__device__ __forceinline__ float bf2f(unsigned short u) {
    union { unsigned int u; float f; } v;
    v.u = ((unsigned int)u) << 16;
    return v.f;
}

// async global->LDS, 16B per lane. LDS dest must be wave-uniform base + lane*16.
__device__ __forceinline__ void async16(const unsigned short* g, unsigned short* l) {
    __builtin_amdgcn_global_load_lds(
        (__attribute__((address_space(1))) void*)(uintptr_t)g,
        (__attribute__((address_space(3))) void*)(uintptr_t)l,
        16, 0, 0);
}

// Tiled skew-symmetric build: one block per upper-tri 64x64 tile pair.
__global__ __launch_bounds__(256) void build_A_tiled(const float* __restrict__ ang,
                                                     unsigned short* __restrict__ A) {
    __shared__ float tile[64][65];
    int b = blockIdx.x;
    int ti = 0, rem = b;
    while (rem >= 32 - ti) { rem -= 32 - ti; ++ti; }
    const int tj = ti + rem;
    const int t  = threadIdx.x;
    const int lj = t & 63;
    const int lw = t >> 6;
    const bool diag = (ti == tj);

#pragma unroll
    for (int m = 0; m < 16; ++m) {
        const int li = lw * 16 + m;
        const int i = ti * 64 + li;
        const int j = tj * 64 + lj;
        float v = 0.0f;
        if (i < j) v = ang[i * (4095 - i) / 2 + (j - i - 1)];
        tile[li][lj] = v;
    }
    __syncthreads();

#pragma unroll
    for (int m = 0; m < 16; ++m) {
        const int li = lw * 16 + m;
        float v;
        if (diag) {
            if (li < lj)      v =  tile[li][lj];
            else if (li > lj) v = -tile[lj][li];
            else              v = 0.0f;
        } else {
            v = tile[li][lj];
        }
        A[(size_t)(ti * 64 + li) * DIM + tj * 64 + lj] = f2bf(v);
    }
    if (!diag) {
#pragma unroll
        for (int m = 0; m < 16; ++m) {
            const int li = lw * 16 + m;
            A[(size_t)(tj * 64 + li) * DIM + ti * 64 + lj] = f2bf(-tile[lj][li]);
        }
    }
}

// fp32 -> bf16, 4 elems/thread
__global__ void cvt_f32_bf16(const float* __restrict__ in, unsigned short* __restrict__ out) {
    int i = (blockIdx.x * 256 + threadIdx.x) * 4;
    const float4 v = *(const float4*)(in + i);
    ushort4 o;
    o.x = f2bf(v.x); o.y = f2bf(v.y); o.z = f2bf(v.z); o.w = f2bf(v.w);
    *(ushort4*)(out + i) = o;
}

// Wt builder: Wt[m*N+n] = (m==n) - 2*A[m*N+n] - sum_k A[m][k]*A[n][k]
// 64x64 tiles (grid 32x32 = 1024 blocks -> ~4 blocks/CU for latency hiding),
// BK=64, XOR swizzle, 256 threads = 4 waves 2x2, each wave 32x32 (2x2 mfma).
__global__ __launch_bounds__(256) void gemm_s64(
        const unsigned short* __restrict__ A,
        unsigned short* __restrict__ Wt) {
    __shared__ __align__(16) unsigned short ldsA[64 * 64];   // 8 KB
    __shared__ __align__(16) unsigned short ldsB[64 * 64];   // 8 KB
    const int K = DIM, N = DIM;

    const int t    = threadIdx.x;
    const int bn   = blockIdx.x * 64;
    const int bm   = blockIdx.y * 64;
    const int lane = t & 63;
    const int wave = t >> 6;
    const int waveM = (wave >> 1) * 32;
    const int waveN = (wave & 1) * 32;
    const int fm = lane & 15;
    const int fq = lane >> 4;

    f32x4 acc[2][2];
#pragma unroll
    for (int i = 0; i < 2; ++i)
#pragma unroll
        for (int j = 0; j < 2; ++j)
            acc[i][j] = (f32x4){0.f, 0.f, 0.f, 0.f};

    const int trow   = t >> 3;                  // 0..31
    const int tchunk = (t & 7) ^ (trow & 7);    // swizzled source k-chunk
    const unsigned short* gA = A + (size_t)(bm + trow) * K + tchunk * 8;
    const unsigned short* gB = A + (size_t)(bn + trow) * K + tchunk * 8;
    const size_t rowskip = (size_t)32 * K;
    unsigned short* lA = ldsA + t * 8;
    unsigned short* lB = ldsB + t * 8;

    for (int kt = 0; kt < K; kt += 64) {
        __syncthreads();
        async16(gA + kt, lA);
        async16(gA + kt + rowskip, lA + 2048);
        async16(gB + kt, lB);
        async16(gB + kt + rowskip, lB + 2048);
        __syncthreads();

#pragma unroll
        for (int ks = 0; ks < 2; ++ks) {
            short8 af[2], bfv[2];
#pragma unroll
            for (int i = 0; i < 2; ++i) {
                const int rowA = waveM + i * 16 + fm;
                const int rowB = waveN + i * 16 + fm;
                af[i]  = *(const short8*)(ldsA + rowA * 64 + (((ks << 2) + fq) ^ (rowA & 7)) * 8);
                bfv[i] = *(const short8*)(ldsB + rowB * 64 + (((ks << 2) + fq) ^ (rowB & 7)) * 8);
            }
#pragma unroll
            for (int i = 0; i < 2; ++i)
#pragma unroll
                for (int j = 0; j < 2; ++j)
                    acc[i][j] = __builtin_amdgcn_mfma_f32_16x16x32_bf16(
                        af[i], bfv[j], acc[i][j], 0, 0, 0);
        }
    }

#pragma unroll
    for (int i = 0; i < 2; ++i) {
#pragma unroll
        for (int j = 0; j < 2; ++j) {
            const int col = bn + waveN + j * 16 + fm;
#pragma unroll
            for (int r = 0; r < 4; ++r) {
                const int row = bm + waveM + i * 16 + fq * 4 + r;
                const float a = bf2f(A[(size_t)row * N + col]);
                const float w = (row == col ? 1.0f : 0.0f) - 2.0f * a - acc[i][j][r];
                Wt[(size_t)row * N + col] = f2bf(w);
            }
        }
    }
}

// Main NT GEMM: out[m*N+n] = sum_k x[m][k]*Wt[n][k] + bias[n]
// 128x128 tile, BK=64 (32 KB LDS), XOR swizzle, 256 threads, conflicts=0 verified.
__global__ __launch_bounds__(256) void gemm_main(
        const unsigned short* __restrict__ Aop,
        const unsigned short* __restrict__ Bop,
        int M, int N, int K,
        const float* __restrict__ bias,
        float* __restrict__ out) {
    __shared__ __align__(16) unsigned short ldsA[128 * 64];
    __shared__ __align__(16) unsigned short ldsB[128 * 64];

    const int t    = threadIdx.x;
    const int bn   = blockIdx.x * 128;
    const int bm   = blockIdx.y * 128;
    const int lane = t & 63;
    const int wave = t >> 6;
    const int waveM = (wave >> 1) * 64;
    const int waveN = (wave & 1) * 64;
    const int fm = lane & 15;
    const int fq = lane >> 4;

    f32x4 acc[4][4];
#pragma unroll
    for (int i = 0; i < 4; ++i)
#pragma unroll
        for (int j = 0; j < 4; ++j)
            acc[i][j] = (f32x4){0.f, 0.f, 0.f, 0.f};

    const int trow   = t >> 3;
    const int tchunk = (t & 7) ^ (trow & 7);
    const unsigned short* gA = Aop + (size_t)(bm + trow) * K + tchunk * 8;
    const unsigned short* gB = Bop + (size_t)(bn + trow) * K + tchunk * 8;
    const size_t rowskip = (size_t)32 * K;
    unsigned short* lA = ldsA + t * 8;
    unsigned short* lB = ldsB + t * 8;

    for (int kt = 0; kt < K; kt += 64) {
        __syncthreads();
#pragma unroll
        for (int i = 0; i < 4; ++i) {
            async16(gA + kt + i * rowskip, lA + i * 2048);
            async16(gB + kt + i * rowskip, lB + i * 2048);
        }
        __syncthreads();

#pragma unroll
        for (int ks = 0; ks < 2; ++ks) {
            short8 af[4], bfv[4];
#pragma unroll
            for (int i = 0; i < 4; ++i) {
                const int rowA = waveM + i * 16 + fm;
                const int rowB = waveN + i * 16 + fm;
                af[i]  = *(const short8*)(ldsA + rowA * 64 + (((ks << 2) + fq) ^ (rowA & 7)) * 8);
                bfv[i] = *(const short8*)(ldsB + rowB * 64 + (((ks << 2) + fq) ^ (rowB & 7)) * 8);
            }
#pragma unroll
            for (int i = 0; i < 4; ++i)
#pragma unroll
                for (int j = 0; j < 4; ++j)
                    acc[i][j] = __builtin_amdgcn_mfma_f32_16x16x32_bf16(
                        af[i], bfv[j], acc[i][j], 0, 0, 0);
        }
    }

#pragma unroll
    for (int i = 0; i < 4; ++i) {
#pragma unroll
        for (int j = 0; j < 4; ++j) {
            const int col = bn + waveN + j * 16 + fm;
#pragma unroll
            for (int r = 0; r < 4; ++r) {
                const int row = bm + waveM + i * 16 + fq * 4 + r;
                out[(size_t)row * N + col] = acc[i][j][r] + bias[col];
            }
        }
    }
}

extern "C" void kernel_launch(void* const* d_in, const int* in_sizes, int n_in,
                              void* d_out, int out_size, void* d_ws, size_t ws_size,
                              hipStream_t stream) {
    const float* x      = (const float*)d_in[0];   // 4*4096*2048
    const float* angles = (const float*)d_in[1];   // 2096128
    const float* bias   = (const float*)d_in[2];   // 2048
    float* out = (float*)d_out;

    char* ws = (char*)d_ws;
    unsigned short* Abf = (unsigned short*)ws;                      //  8 MB: A bf16
    unsigned short* Wt  = (unsigned short*)(ws + (8u << 20));       //  8 MB: W^T bf16
    unsigned short* xbf = (unsigned short*)(ws + (16u << 20));      // 64 MB: x bf16

    const int M = 4 * 4096;
    const int n_elem_x = M * DIM;

    build_A_tiled<<<528, 256, 0, stream>>>(angles, Abf);
    cvt_f32_bf16<<<(n_elem_x / 4) / 256, 256, 0, stream>>>(x, xbf);

    // Wt = I - 2A - A*A^T  (2048^3, 1024 blocks)
    gemm_s64<<<dim3(DIM / 64, DIM / 64), 256, 0, stream>>>(Abf, Wt);

    // out = x @ W + bias  via NT against Wt  (16384 x 2048 x 2048)
    gemm_main<<<dim3(DIM / 128, M / 128), 256, 0, stream>>>(
        xbf, Wt, M, DIM, DIM, bias, out);
}